// Round 1
// baseline (1353.906 us; speedup 1.0000x reference)
//
#include <hip/hip_runtime.h>
#include <math.h>

#define SS 9
#define EE 32
#define TPB 256
#define NW (TPB / 64)

// d_ws float offsets (derived weights, computed by prep kernel each launch)
#define WS_M0   0      // M_h[e][e2], h-major, 2*1024
#define WS_PT0  2048   // PT_h[e][f] = P_h[f][e], 2*1024
#define WS_UB   4096   // ub_h[e],  2*32
#define WS_U    4160   // u_h[e],   2*32
#define WS_BO2  4224   // bo2[f],   32
#define WS_C    4256   // c_h,      2

// qk[h][s]*0.25-scale is folded:
//   0.25*qk = c_h + q.u_h + k_s.(ub_h + q^T M_h)
//   out[f]  = bo2[f] + sum_h vbar_h . PT_h[:,f]   (uses sum_s p = 1)
__global__ void gauss_prep_kernel(const float* __restrict__ ipw,
                                  const float* __restrict__ ipb,
                                  const float* __restrict__ opw,
                                  const float* __restrict__ opb,
                                  float* __restrict__ dw) {
  const int tid = threadIdx.x;
  // M_h[e][e2] = 0.25 * sum_d Wq[h*16+d][e] * Wk[h*16+d][e2]
  for (int idx = tid; idx < 2048; idx += TPB) {
    const int h = idx >> 10, e = (idx >> 5) & 31, e2 = idx & 31;
    float acc = 0.f;
    for (int d = 0; d < 16; ++d)
      acc += ipw[(h * 16 + d) * 32 + e] * ipw[(32 + h * 16 + d) * 32 + e2];
    dw[WS_M0 + idx] = 0.25f * acc;
  }
  // PT_h[e][f] = sum_d Wo[f][h*16+d] * Wv[h*16+d][e]
  for (int idx = tid; idx < 2048; idx += TPB) {
    const int h = idx >> 10, e = (idx >> 5) & 31, f = idx & 31;
    float acc = 0.f;
    for (int d = 0; d < 16; ++d)
      acc += opw[f * 32 + h * 16 + d] * ipw[(64 + h * 16 + d) * 32 + e];
    dw[WS_PT0 + idx] = acc;
  }
  if (tid < 64) {
    const int h = tid >> 5, e = tid & 31;
    float a_ub = 0.f, a_u = 0.f;
    for (int d = 0; d < 16; ++d) {
      a_ub += ipb[h * 16 + d] * ipw[(32 + h * 16 + d) * 32 + e];
      a_u  += ipw[(h * 16 + d) * 32 + e] * ipb[32 + h * 16 + d];
    }
    dw[WS_UB + tid] = 0.25f * a_ub;
    dw[WS_U + tid]  = 0.25f * a_u;
  } else if (tid < 96) {
    const int f = tid - 64;
    float acc = opb[f];
    for (int j = 0; j < 32; ++j) acc += ipb[64 + j] * opw[f * 32 + j];
    dw[WS_BO2 + f] = acc;
  } else if (tid < 98) {
    const int h = tid - 96;
    float acc = 0.f;
    for (int d = 0; d < 16; ++d) acc += ipb[h * 16 + d] * ipb[32 + h * 16 + d];
    dw[WS_C + h] = 0.25f * acc;
  }
}

// Wave-synchronous version: zero __syncthreads. Each wave stages its own
// 64 rows into a private swizzled LDS region (DS ops within a wave are
// in-order; wave_barrier pins compiler ordering). Global loads for slice
// s+1 are issued before slice s is consumed (1-deep register prefetch),
// so HBM latency hides under compute + other waves.
__global__ __launch_bounds__(TPB, 3) void gauss_attn_kernel(
    const float* __restrict__ query,
    const float* __restrict__ key,
    const float* __restrict__ value,
    const float* __restrict__ gauss,
    const float* __restrict__ dw,
    float* __restrict__ out) {
  // Per-wave tile: 64 rows x 8 float4 chunks. Data chunk (r,j) lives at
  // slot (r<<3) | (j ^ (r&7)): 16B-aligned ds_*_b128, conflict-free on
  // both the coalesced-write side and the per-row-read side.
  __shared__ float4 kt4[NW][512];   // 32 KB total

  const int tid = threadIdx.x;
  const int w  = tid >> 6;          // wave id
  const int l  = tid & 63;          // lane; also this thread's row-in-wave
  const int l3 = l >> 3;            // staging row-group
  const int j7 = l & 7;             // staging chunk-in-row
  const long b0 = (long)blockIdx.x * TPB;
  const long rw = b0 + (long)w * 64;           // first row of this wave
  // staging slot for chunk-iteration i is  i*64 + sbase
  const int sbase = (l3 << 3) | (j7 ^ l3);

  // ---- issue ALL prologue loads first (q, k s=0, gauss), then stage q ----
  float4 qld[8];
  {
    const float4* qp = (const float4*)(query + rw * EE);
    #pragma unroll
    for (int i = 0; i < 8; ++i) qld[i] = qp[i * 64 + l];
  }
  const float* kp = key   + (rw + l3) * (long)(SS * EE) + j7 * 4;
  const float* vp = value + (rw + l3) * (long)(SS * EE) + j7 * 4;
  float4 pre[2][8];
  #pragma unroll
  for (int i = 0; i < 8; ++i)
    pre[0][i] = *(const float4*)(kp + i * (8 * SS * EE));
  float gw[SS];
  {
    const float* gp = gauss + (rw + l) * SS;
    #pragma unroll
    for (int s = 0; s < SS; ++s) gw[s] = gp[s];
  }

  #pragma unroll
  for (int i = 0; i < 8; ++i) kt4[w][i * 64 + sbase] = qld[i];
  __builtin_amdgcn_wave_barrier();

  float qreg[32];
  #pragma unroll
  for (int j = 0; j < 8; ++j) {
    const float4 v = kt4[w][(l << 3) | (j ^ j7)];
    qreg[4 * j] = v.x; qreg[4 * j + 1] = v.y;
    qreg[4 * j + 2] = v.z; qreg[4 * j + 3] = v.w;
  }
  __builtin_amdgcn_wave_barrier();

  // t0[h] = c_h + q . u_h   (uniform weight indices -> s_load/SGPR operands)
  float t00 = dw[WS_C + 0], t01 = dw[WS_C + 1];
  #pragma unroll
  for (int e = 0; e < 32; ++e) {
    t00 += qreg[e] * dw[WS_U + e];
    t01 += qreg[e] * dw[WS_U + 32 + e];
  }

  // wv_h = ub_h + q^T M_h   (k s=0 + gauss loads in flight under this)
  float wv0[32], wv1[32];
  #pragma unroll
  for (int e2 = 0; e2 < 32; ++e2) {
    wv0[e2] = dw[WS_UB + e2];
    wv1[e2] = dw[WS_UB + 32 + e2];
  }
  #pragma unroll
  for (int e = 0; e < 32; ++e) {
    const float qe = qreg[e];
    #pragma unroll
    for (int e2 = 0; e2 < 32; ++e2) {
      wv0[e2] += qe * dw[WS_M0 + e * 32 + e2];
      wv1[e2] += qe * dw[WS_M0 + 1024 + e * 32 + e2];
    }
  }

  #pragma unroll
  for (int s = 0; s < SS; ++s) gw[s] = __expf(-10.0f * gw[s]);

  // ---- K phase: per-wave stage + own-row dot, 1-deep prefetch ----
  float qk0[SS], qk1[SS];
  #pragma unroll
  for (int s = 0; s < SS; ++s) {
    const int c = s & 1;
    if (s + 1 < SS) {
      #pragma unroll
      for (int i = 0; i < 8; ++i)
        pre[c ^ 1][i] = *(const float4*)(kp + i * (8 * SS * EE) + (s + 1) * EE);
    } else {
      // prefetch v(s=0) for the V phase; lands during softmax
      #pragma unroll
      for (int i = 0; i < 8; ++i)
        pre[c ^ 1][i] = *(const float4*)(vp + i * (8 * SS * EE));
    }
    #pragma unroll
    for (int i = 0; i < 8; ++i) kt4[w][i * 64 + sbase] = pre[c][i];
    __builtin_amdgcn_wave_barrier();
    float a0 = t00, a1 = t01;
    #pragma unroll
    for (int j = 0; j < 8; ++j) {
      const float4 v = kt4[w][(l << 3) | (j ^ j7)];
      a0 += wv0[4*j]*v.x + wv0[4*j+1]*v.y + wv0[4*j+2]*v.z + wv0[4*j+3]*v.w;
      a1 += wv1[4*j]*v.x + wv1[4*j+1]*v.y + wv1[4*j+2]*v.z + wv1[4*j+3]*v.w;
    }
    qk0[s] = a0; qk1[s] = a1;
    __builtin_amdgcn_wave_barrier();
  }

  // ---- gauss-weighted softmax over s, per head (per-thread registers) ----
  float p0[SS], p1[SS];
  {
    float m0 = -1e30f, m1 = -1e30f;
    #pragma unroll
    for (int s = 0; s < SS; ++s) {
      qk0[s] *= gw[s]; qk1[s] *= gw[s];
      m0 = fmaxf(m0, qk0[s]); m1 = fmaxf(m1, qk1[s]);
    }
    float l0 = 0.f, l1 = 0.f;
    #pragma unroll
    for (int s = 0; s < SS; ++s) {
      p0[s] = __expf(qk0[s] - m0); l0 += p0[s];
      p1[s] = __expf(qk1[s] - m1); l1 += p1[s];
    }
    const float r0 = 1.f / l0, r1 = 1.f / l1;
    #pragma unroll
    for (int s = 0; s < SS; ++s) { p0[s] *= r0; p1[s] *= r1; }
  }

  // ---- V phase: vbar_h[e] = sum_s p[h][s] * v_s[e] ----
  float vb0[32], vb1[32];
  #pragma unroll
  for (int e = 0; e < 32; ++e) { vb0[e] = 0.f; vb1[e] = 0.f; }
  #pragma unroll
  for (int s = 0; s < SS; ++s) {
    const int c = (s + 1) & 1;   // s=0 was prefetched into pre[1]
    if (s + 1 < SS) {
      #pragma unroll
      for (int i = 0; i < 8; ++i)
        pre[c ^ 1][i] = *(const float4*)(vp + i * (8 * SS * EE) + (s + 1) * EE);
    }
    #pragma unroll
    for (int i = 0; i < 8; ++i) kt4[w][i * 64 + sbase] = pre[c][i];
    __builtin_amdgcn_wave_barrier();
    const float w0 = p0[s], w1 = p1[s];
    #pragma unroll
    for (int j = 0; j < 8; ++j) {
      const float4 v = kt4[w][(l << 3) | (j ^ j7)];
      vb0[4*j]   += w0 * v.x; vb0[4*j+1] += w0 * v.y;
      vb0[4*j+2] += w0 * v.z; vb0[4*j+3] += w0 * v.w;
      vb1[4*j]   += w1 * v.x; vb1[4*j+1] += w1 * v.y;
      vb1[4*j+2] += w1 * v.z; vb1[4*j+3] += w1 * v.w;
    }
    __builtin_amdgcn_wave_barrier();
  }

  // ---- fused out-proj: out[f] = bo2[f] + sum_e vb0[e]*PT0[e][f] + vb1[e]*PT1[e][f]
  float o[32];
  #pragma unroll
  for (int f = 0; f < 32; ++f) o[f] = dw[WS_BO2 + f];
  #pragma unroll
  for (int e = 0; e < 32; ++e) {
    const float x0 = vb0[e], x1 = vb1[e];
    #pragma unroll
    for (int f = 0; f < 32; ++f) {
      o[f] += x0 * dw[WS_PT0 + e * 32 + f];
      o[f] += x1 * dw[WS_PT0 + 1024 + e * 32 + f];
    }
  }

  // ---- coalesced store via the per-wave tile ----
  #pragma unroll
  for (int j = 0; j < 8; ++j)
    kt4[w][(l << 3) | (j ^ j7)] =
        make_float4(o[4*j], o[4*j+1], o[4*j+2], o[4*j+3]);
  __builtin_amdgcn_wave_barrier();
  {
    float4* op = (float4*)(out + rw * EE);
    #pragma unroll
    for (int i = 0; i < 8; ++i) op[i * 64 + l] = kt4[w][i * 64 + sbase];
  }
}

extern "C" void kernel_launch(void* const* d_in, const int* in_sizes, int n_in,
                              void* d_out, int out_size, void* d_ws, size_t ws_size,
                              hipStream_t stream) {
  const float* query = (const float*)d_in[0];
  const float* key   = (const float*)d_in[1];
  const float* value = (const float*)d_in[2];
  const float* gauss = (const float*)d_in[3];
  const float* ipw   = (const float*)d_in[4];
  const float* ipb   = (const float*)d_in[5];
  const float* opw   = (const float*)d_in[6];
  const float* opb   = (const float*)d_in[7];
  float* out = (float*)d_out;
  float* dw  = (float*)d_ws;   // needs 4258 floats (~17 KB)

  const int n = in_sizes[0] / EE;  // 262144 batches
  gauss_prep_kernel<<<1, TPB, 0, stream>>>(ipw, ipb, opw, opb, dw);
  gauss_attn_kernel<<<n / TPB, TPB, 0, stream>>>(query, key, value, gauss, dw, out);
}

// Round 2
// 677.419 us; speedup vs baseline: 1.9986x; 1.9986x over previous
//
#include <hip/hip_runtime.h>
#include <math.h>

#define SS 9
#define EE 32
#define TPB 256

// d_ws float offsets (derived weights, computed by prep kernel each launch)
#define WS_M0   0      // M_h[e][e2], h-major, 2*1024
#define WS_PT0  2048   // PT_h[e][f] = P_h[f][e], 2*1024
#define WS_UB   4096   // ub_h[e],  2*32
#define WS_U    4160   // u_h[e],   2*32
#define WS_BO2  4224   // bo2[f],   32
#define WS_C    4256   // c_h,      2

// qk[h][s]*0.25-scale is folded:
//   0.25*qk = c_h + q.u_h + k_s.(ub_h + q^T M_h)
//   out[f]  = bo2[f] + sum_h vbar_h . PT_h[:,f]   (uses sum_s p = 1)
__global__ void gauss_prep_kernel(const float* __restrict__ ipw,
                                  const float* __restrict__ ipb,
                                  const float* __restrict__ opw,
                                  const float* __restrict__ opb,
                                  float* __restrict__ dw) {
  const int tid = threadIdx.x;
  // M_h[e][e2] = 0.25 * sum_d Wq[h*16+d][e] * Wk[h*16+d][e2]
  for (int idx = tid; idx < 2048; idx += TPB) {
    const int h = idx >> 10, e = (idx >> 5) & 31, e2 = idx & 31;
    float acc = 0.f;
    for (int d = 0; d < 16; ++d)
      acc += ipw[(h * 16 + d) * 32 + e] * ipw[(32 + h * 16 + d) * 32 + e2];
    dw[WS_M0 + idx] = 0.25f * acc;
  }
  // PT_h[e][f] = sum_d Wo[f][h*16+d] * Wv[h*16+d][e]
  for (int idx = tid; idx < 2048; idx += TPB) {
    const int h = idx >> 10, e = (idx >> 5) & 31, f = idx & 31;
    float acc = 0.f;
    for (int d = 0; d < 16; ++d)
      acc += opw[f * 32 + h * 16 + d] * ipw[(64 + h * 16 + d) * 32 + e];
    dw[WS_PT0 + idx] = acc;
  }
  if (tid < 64) {
    const int h = tid >> 5, e = tid & 31;
    float a_ub = 0.f, a_u = 0.f;
    for (int d = 0; d < 16; ++d) {
      a_ub += ipb[h * 16 + d] * ipw[(32 + h * 16 + d) * 32 + e];
      a_u  += ipw[(h * 16 + d) * 32 + e] * ipb[32 + h * 16 + d];
    }
    dw[WS_UB + tid] = 0.25f * a_ub;
    dw[WS_U + tid]  = 0.25f * a_u;
  } else if (tid < 96) {
    const int f = tid - 64;
    float acc = opb[f];
    for (int j = 0; j < 32; ++j) acc += ipb[64 + j] * opw[f * 32 + j];
    dw[WS_BO2 + f] = acc;
  } else if (tid < 98) {
    const int h = tid - 96;
    float acc = 0.f;
    for (int d = 0; d < 16; ++d) acc += ipb[h * 16 + d] * ipb[32 + h * 16 + d];
    dw[WS_C + h] = 0.25f * acc;
  }
}

// No-LDS version: one batch row per thread, everything contiguous per lane.
// K/V rows are 1152 contiguous bytes each (all 9 slices) -> one base address
// + 13-bit immediate offsets; every fetched cache line is fully consumed by
// the same thread. Zero barriers, zero LDS, zero transposes: all latency is
// hidden by 16 waves/CU and free compiler scheduling.
__global__ __launch_bounds__(TPB) void gauss_attn_kernel(
    const float* __restrict__ query,
    const float* __restrict__ key,
    const float* __restrict__ value,
    const float* __restrict__ gauss,
    const float* __restrict__ dw,
    float* __restrict__ out) {
  const int tid = threadIdx.x;
  const long b = (long)blockIdx.x * TPB + tid;

  // ---- q row: 128B contiguous per lane ----
  float qreg[32];
  {
    const float4* qp = (const float4*)(query + b * EE);
    #pragma unroll
    for (int i = 0; i < 8; ++i) {
      const float4 v = qp[i];
      qreg[4 * i] = v.x; qreg[4 * i + 1] = v.y;
      qreg[4 * i + 2] = v.z; qreg[4 * i + 3] = v.w;
    }
  }
  // ---- gauss row: 36B per lane (lines shared by neighbor lanes) ----
  float gw[SS];
  {
    const float* gp = gauss + b * SS;
    #pragma unroll
    for (int s = 0; s < SS; ++s) gw[s] = gp[s];
  }

  // t0[h] = c_h + q . u_h   (uniform weight indices -> s_load/SGPR operands)
  float t00 = dw[WS_C + 0], t01 = dw[WS_C + 1];
  #pragma unroll
  for (int e = 0; e < 32; ++e) {
    t00 += qreg[e] * dw[WS_U + e];
    t01 += qreg[e] * dw[WS_U + 32 + e];
  }

  // wv_h = ub_h + q^T M_h   (K loads drift up under this via scheduler)
  float wv0[32], wv1[32];
  #pragma unroll
  for (int e2 = 0; e2 < 32; ++e2) {
    wv0[e2] = dw[WS_UB + e2];
    wv1[e2] = dw[WS_UB + 32 + e2];
  }
  #pragma unroll
  for (int e = 0; e < 32; ++e) {
    const float qe = qreg[e];
    #pragma unroll
    for (int e2 = 0; e2 < 32; ++e2) {
      wv0[e2] += qe * dw[WS_M0 + e * 32 + e2];
      wv1[e2] += qe * dw[WS_M0 + 1024 + e * 32 + e2];
    }
  }

  #pragma unroll
  for (int s = 0; s < SS; ++s) gw[s] = __expf(-10.0f * gw[s]);

  // ---- K phase: per-lane contiguous row, one slice at a time ----
  float qk0[SS], qk1[SS];
  {
    const float4* kp = (const float4*)(key + b * (long)(SS * EE));
    #pragma unroll
    for (int s = 0; s < SS; ++s) {
      float a0 = t00, a1 = t01;
      #pragma unroll
      for (int j = 0; j < 8; ++j) {
        const float4 v = kp[s * 8 + j];
        a0 += wv0[4*j]*v.x + wv0[4*j+1]*v.y + wv0[4*j+2]*v.z + wv0[4*j+3]*v.w;
        a1 += wv1[4*j]*v.x + wv1[4*j+1]*v.y + wv1[4*j+2]*v.z + wv1[4*j+3]*v.w;
      }
      qk0[s] = a0; qk1[s] = a1;
    }
  }

  // ---- gauss-weighted softmax over s, per head ----
  float p0[SS], p1[SS];
  {
    float m0 = -1e30f, m1 = -1e30f;
    #pragma unroll
    for (int s = 0; s < SS; ++s) {
      qk0[s] *= gw[s]; qk1[s] *= gw[s];
      m0 = fmaxf(m0, qk0[s]); m1 = fmaxf(m1, qk1[s]);
    }
    float l0 = 0.f, l1 = 0.f;
    #pragma unroll
    for (int s = 0; s < SS; ++s) {
      p0[s] = __expf(qk0[s] - m0); l0 += p0[s];
      p1[s] = __expf(qk1[s] - m1); l1 += p1[s];
    }
    const float r0 = 1.f / l0, r1 = 1.f / l1;
    #pragma unroll
    for (int s = 0; s < SS; ++s) { p0[s] *= r0; p1[s] *= r1; }
  }

  // ---- V phase: vbar_h[e] = sum_s p[h][s] * v_s[e] ----
  float vb0[32], vb1[32];
  #pragma unroll
  for (int e = 0; e < 32; ++e) { vb0[e] = 0.f; vb1[e] = 0.f; }
  {
    const float4* vp = (const float4*)(value + b * (long)(SS * EE));
    #pragma unroll
    for (int s = 0; s < SS; ++s) {
      const float w0 = p0[s], w1 = p1[s];
      #pragma unroll
      for (int j = 0; j < 8; ++j) {
        const float4 v = vp[s * 8 + j];
        vb0[4*j]   += w0 * v.x; vb0[4*j+1] += w0 * v.y;
        vb0[4*j+2] += w0 * v.z; vb0[4*j+3] += w0 * v.w;
        vb1[4*j]   += w1 * v.x; vb1[4*j+1] += w1 * v.y;
        vb1[4*j+2] += w1 * v.z; vb1[4*j+3] += w1 * v.w;
      }
    }
  }

  // ---- fused out-proj: out[f] = bo2[f] + sum_e vb0[e]*PT0[e][f] + vb1[e]*PT1[e][f]
  float o[32];
  #pragma unroll
  for (int f = 0; f < 32; ++f) o[f] = dw[WS_BO2 + f];
  #pragma unroll
  for (int e = 0; e < 32; ++e) {
    const float x0 = vb0[e], x1 = vb1[e];
    #pragma unroll
    for (int f = 0; f < 32; ++f) {
      o[f] += x0 * dw[WS_PT0 + e * 32 + f];
      o[f] += x1 * dw[WS_PT0 + 1024 + e * 32 + f];
    }
  }

  // ---- store: 128B contiguous per lane (full lines, all bytes written) ----
  {
    float4* op = (float4*)(out + b * EE);
    #pragma unroll
    for (int i = 0; i < 8; ++i)
      op[i] = make_float4(o[4*i], o[4*i+1], o[4*i+2], o[4*i+3]);
  }
}

extern "C" void kernel_launch(void* const* d_in, const int* in_sizes, int n_in,
                              void* d_out, int out_size, void* d_ws, size_t ws_size,
                              hipStream_t stream) {
  const float* query = (const float*)d_in[0];
  const float* key   = (const float*)d_in[1];
  const float* value = (const float*)d_in[2];
  const float* gauss = (const float*)d_in[3];
  const float* ipw   = (const float*)d_in[4];
  const float* ipb   = (const float*)d_in[5];
  const float* opw   = (const float*)d_in[6];
  const float* opb   = (const float*)d_in[7];
  float* out = (float*)d_out;
  float* dw  = (float*)d_ws;   // needs 4258 floats (~17 KB)

  const int n = in_sizes[0] / EE;  // 262144 batches
  gauss_prep_kernel<<<1, TPB, 0, stream>>>(ipw, ipb, opw, opb, dw);
  gauss_attn_kernel<<<n / TPB, TPB, 0, stream>>>(query, key, value, gauss, dw, out);
}